// Round 1
// baseline (32.728 us; speedup 1.0000x reference)
//
#include <hip/hip_runtime.h>

#define BATCH 16384
#define DIM 1024
#define NLAYERS 4

// One block per row (256 threads x float4 = 1024 cols).
// x0 and xl live in registers across all layers: 1 read + 1 write of the
// 64MB activation, W/b are L2-resident broadcasts.
__global__ __launch_bounds__(256) void crossnet_kernel(
    const float* __restrict__ x0,
    const float* __restrict__ W,
    const float* __restrict__ b,
    float* __restrict__ out)
{
    const int row  = blockIdx.x;
    const int tid  = threadIdx.x;
    const int lane = tid & 63;
    const int wave = tid >> 6;

    // double-buffered cross-wave reduction slots (one sync per layer)
    __shared__ float red[2][4];

    const float4* x0v = reinterpret_cast<const float4*>(x0 + (size_t)row * DIM);
    float4 x  = x0v[tid];
    float4 xl = x;

    // Preload W/b fragments for this thread's 4 columns, all 4 layers.
    float4 w[NLAYERS], bb[NLAYERS];
#pragma unroll
    for (int l = 0; l < NLAYERS; ++l) {
        w[l]  = reinterpret_cast<const float4*>(W + l * DIM)[tid];
        bb[l] = reinterpret_cast<const float4*>(b + l * DIM)[tid];
    }

#pragma unroll
    for (int l = 0; l < NLAYERS; ++l) {
        // partial dot: xl . W[l] over this thread's 4 columns
        float p = xl.x * w[l].x + xl.y * w[l].y + xl.z * w[l].z + xl.w * w[l].w;
        // 64-lane butterfly reduce
#pragma unroll
        for (int off = 32; off > 0; off >>= 1)
            p += __shfl_xor(p, off, 64);
        if (lane == 0) red[l & 1][wave] = p;
        __syncthreads();
        const float s = red[l & 1][0] + red[l & 1][1] + red[l & 1][2] + red[l & 1][3];
        // xl = x0 * s + b[l] + xl
        xl.x = fmaf(x.x, s, bb[l].x + xl.x);
        xl.y = fmaf(x.y, s, bb[l].y + xl.y);
        xl.z = fmaf(x.z, s, bb[l].z + xl.z);
        xl.w = fmaf(x.w, s, bb[l].w + xl.w);
        // next layer writes red[(l+1)&1]; reads of red[l&1] are complete
        // before the next layer's __syncthreads -> no extra barrier needed.
    }

    reinterpret_cast<float4*>(out + (size_t)row * DIM)[tid] = xl;
}

extern "C" void kernel_launch(void* const* d_in, const int* in_sizes, int n_in,
                              void* d_out, int out_size, void* d_ws, size_t ws_size,
                              hipStream_t stream) {
    const float* x0 = (const float*)d_in[0];
    const float* W  = (const float*)d_in[1];
    const float* b  = (const float*)d_in[2];
    float* out      = (float*)d_out;

    crossnet_kernel<<<BATCH, 256, 0, stream>>>(x0, W, b, out);
}

// Round 2
// 26.308 us; speedup vs baseline: 1.2440x; 1.2440x over previous
//
#include <hip/hip_runtime.h>

#define BATCH   16384
#define DIM     1024
#define NLAYERS 4
#define NF4     (DIM / 4)     // 256 float4 per row
#define THREADS 256           // 4 waves per block
#define NBLOCKS 2048          // 8192 waves -> 2 rows per wave

// Algebraic collapse: x_L = alpha * x0 + bsum, where
//   bsum = sum_l b[l]
//   alpha = 1 + sum_l s_l,  s_l = alpha_l * d_l + c_l
//   d_l = x0 . W[l]                     (per row, all 4 vs the SAME x0)
//   c_l = (sum_{k<l} b[k]) . W[l]       (row-independent, computed per block)
// -> one wave-level butterfly reduce per row, zero barriers in the row loop.
__global__ __launch_bounds__(THREADS) void crossnet_kernel(
    const float* __restrict__ x0,
    const float* __restrict__ W,
    const float* __restrict__ b,
    float* __restrict__ out)
{
    __shared__ float4 lW[NLAYERS * NF4];   // 16 KB: W staged for per-row reads
    __shared__ float4 lBsum[NF4];          //  4 KB
    __shared__ float  redc[3][4];

    const int tid  = threadIdx.x;
    const int lane = tid & 63;
    const int wv   = tid >> 6;

    const float4* Wv = reinterpret_cast<const float4*>(W);
    const float4* bv = reinterpret_cast<const float4*>(b);

    // ---- per-block prologue: stage W, build bsum and c_l constants ----
#pragma unroll
    for (int i = 0; i < NLAYERS * NF4 / THREADS; ++i)
        lW[tid + i * THREADS] = Wv[tid + i * THREADS];

    // thread t owns float4-column t for the constant computation
    float4 b0 = bv[0 * NF4 + tid];
    float4 b1 = bv[1 * NF4 + tid];
    float4 b2 = bv[2 * NF4 + tid];
    float4 b3 = bv[3 * NF4 + tid];
    float4 w1 = Wv[1 * NF4 + tid];
    float4 w2 = Wv[2 * NF4 + tid];
    float4 w3 = Wv[3 * NF4 + tid];

    float4 pre = b0;   // prefix sum of biases
    float c1 = pre.x * w1.x + pre.y * w1.y + pre.z * w1.z + pre.w * w1.w;
    pre.x += b1.x; pre.y += b1.y; pre.z += b1.z; pre.w += b1.w;
    float c2 = pre.x * w2.x + pre.y * w2.y + pre.z * w2.z + pre.w * w2.w;
    pre.x += b2.x; pre.y += b2.y; pre.z += b2.z; pre.w += b2.w;
    float c3 = pre.x * w3.x + pre.y * w3.y + pre.z * w3.z + pre.w * w3.w;
    pre.x += b3.x; pre.y += b3.y; pre.z += b3.z; pre.w += b3.w;
    lBsum[tid] = pre;  // pre == bsum at this column

#pragma unroll
    for (int off = 32; off; off >>= 1) {
        c1 += __shfl_xor(c1, off, 64);
        c2 += __shfl_xor(c2, off, 64);
        c3 += __shfl_xor(c3, off, 64);
    }
    if (lane == 0) { redc[0][wv] = c1; redc[1][wv] = c2; redc[2][wv] = c3; }
    __syncthreads();
    const float cp1 = redc[0][0] + redc[0][1] + redc[0][2] + redc[0][3];
    const float cp2 = redc[1][0] + redc[1][1] + redc[1][2] + redc[1][3];
    const float cp3 = redc[2][0] + redc[2][1] + redc[2][2] + redc[2][3];

    // per-lane bsum fragments (registers, reused across rows)
    float4 bs[4];
#pragma unroll
    for (int j = 0; j < 4; ++j) bs[j] = lBsum[j * 64 + lane];

    // ---- row loop: one wave per row, barrier-free ----
    const int gw = blockIdx.x * (THREADS / 64) + wv;
    const int nw = NBLOCKS * (THREADS / 64);

    for (int row = gw; row < BATCH; row += nw) {
        const float4* xv = reinterpret_cast<const float4*>(x0) + (size_t)row * NF4;
        float4 x[4];
#pragma unroll
        for (int j = 0; j < 4; ++j) x[j] = xv[j * 64 + lane];

        float d0 = 0.f, d1 = 0.f, d2 = 0.f, d3 = 0.f;
#pragma unroll
        for (int j = 0; j < 4; ++j) {
            const int fi = j * 64 + lane;
            float4 a0 = lW[0 * NF4 + fi];
            float4 a1 = lW[1 * NF4 + fi];
            float4 a2 = lW[2 * NF4 + fi];
            float4 a3 = lW[3 * NF4 + fi];
            d0 += x[j].x * a0.x + x[j].y * a0.y + x[j].z * a0.z + x[j].w * a0.w;
            d1 += x[j].x * a1.x + x[j].y * a1.y + x[j].z * a1.z + x[j].w * a1.w;
            d2 += x[j].x * a2.x + x[j].y * a2.y + x[j].z * a2.z + x[j].w * a2.w;
            d3 += x[j].x * a3.x + x[j].y * a3.y + x[j].z * a3.z + x[j].w * a3.w;
        }
#pragma unroll
        for (int off = 32; off; off >>= 1) {
            d0 += __shfl_xor(d0, off, 64);
            d1 += __shfl_xor(d1, off, 64);
            d2 += __shfl_xor(d2, off, 64);
            d3 += __shfl_xor(d3, off, 64);
        }

        float alpha = 1.0f;
        float s0 = alpha * d0;              alpha += s0;
        float s1 = fmaf(alpha, d1, cp1);    alpha += s1;
        float s2 = fmaf(alpha, d2, cp2);    alpha += s2;
        float s3 = fmaf(alpha, d3, cp3);    alpha += s3;

        float4* ov = reinterpret_cast<float4*>(out) + (size_t)row * NF4;
#pragma unroll
        for (int j = 0; j < 4; ++j) {
            float4 o;
            o.x = fmaf(alpha, x[j].x, bs[j].x);
            o.y = fmaf(alpha, x[j].y, bs[j].y);
            o.z = fmaf(alpha, x[j].z, bs[j].z);
            o.w = fmaf(alpha, x[j].w, bs[j].w);
            ov[j * 64 + lane] = o;
        }
    }
}

extern "C" void kernel_launch(void* const* d_in, const int* in_sizes, int n_in,
                              void* d_out, int out_size, void* d_ws, size_t ws_size,
                              hipStream_t stream) {
    const float* x0 = (const float*)d_in[0];
    const float* W  = (const float*)d_in[1];
    const float* b  = (const float*)d_in[2];
    float* out      = (float*)d_out;

    crossnet_kernel<<<NBLOCKS, THREADS, 0, stream>>>(x0, W, b, out);
}

// Round 3
// 25.973 us; speedup vs baseline: 1.2601x; 1.0129x over previous
//
#include <hip/hip_runtime.h>

#define BATCH   16384
#define DIM     1024
#define NLAYERS 4
#define NF4     (DIM / 4)     // 256 float4 per row
#define THREADS 256           // 4 waves per block
#define NBLOCKS 2048          // 8192 waves x 2 concurrent rows = 16384 rows

// x_L = alpha * x0 + bsum;  alpha = 1 + sum_l s_l,
// s_l = alpha_l * (x0 . W[l]) + c_l,  c_l = (sum_{k<l} b[k]) . W[l].
// Each wave handles TWO rows concurrently: 8 loads in flight, shared W
// ds_reads, 8 interleaved reduce chains -> latency-pipelined streaming.
__global__ __launch_bounds__(THREADS) void crossnet_kernel(
    const float* __restrict__ x0,
    const float* __restrict__ W,
    const float* __restrict__ b,
    float* __restrict__ out)
{
    __shared__ float4 lW[NLAYERS * NF4];   // 16 KB staged W
    __shared__ float4 lBsum[NF4];          //  4 KB
    __shared__ float  redc[3][4];

    const int tid  = threadIdx.x;
    const int lane = tid & 63;
    const int wv   = tid >> 6;

    const float4* Wv = reinterpret_cast<const float4*>(W);
    const float4* bv = reinterpret_cast<const float4*>(b);

    // ---- per-block prologue: stage W, build bsum and c_l constants ----
#pragma unroll
    for (int i = 0; i < NLAYERS * NF4 / THREADS; ++i)
        lW[tid + i * THREADS] = Wv[tid + i * THREADS];

    float4 b0 = bv[0 * NF4 + tid];
    float4 b1 = bv[1 * NF4 + tid];
    float4 b2 = bv[2 * NF4 + tid];
    float4 b3 = bv[3 * NF4 + tid];
    float4 w1 = Wv[1 * NF4 + tid];
    float4 w2 = Wv[2 * NF4 + tid];
    float4 w3 = Wv[3 * NF4 + tid];

    float4 pre = b0;
    float c1 = pre.x * w1.x + pre.y * w1.y + pre.z * w1.z + pre.w * w1.w;
    pre.x += b1.x; pre.y += b1.y; pre.z += b1.z; pre.w += b1.w;
    float c2 = pre.x * w2.x + pre.y * w2.y + pre.z * w2.z + pre.w * w2.w;
    pre.x += b2.x; pre.y += b2.y; pre.z += b2.z; pre.w += b2.w;
    float c3 = pre.x * w3.x + pre.y * w3.y + pre.z * w3.z + pre.w * w3.w;
    pre.x += b3.x; pre.y += b3.y; pre.z += b3.z; pre.w += b3.w;
    lBsum[tid] = pre;

#pragma unroll
    for (int off = 32; off; off >>= 1) {
        c1 += __shfl_xor(c1, off, 64);
        c2 += __shfl_xor(c2, off, 64);
        c3 += __shfl_xor(c3, off, 64);
    }
    if (lane == 0) { redc[0][wv] = c1; redc[1][wv] = c2; redc[2][wv] = c3; }
    __syncthreads();
    const float cp1 = redc[0][0] + redc[0][1] + redc[0][2] + redc[0][3];
    const float cp2 = redc[1][0] + redc[1][1] + redc[1][2] + redc[1][3];
    const float cp3 = redc[2][0] + redc[2][1] + redc[2][2] + redc[2][3];

    float4 bs[4];
#pragma unroll
    for (int j = 0; j < 4; ++j) bs[j] = lBsum[j * 64 + lane];

    // ---- two rows per wave, processed concurrently, no loop ----
    const int gw = blockIdx.x * (THREADS / 64) + wv;   // 0..8191
    const size_t r0 = (size_t)(2 * gw);
    const size_t r1 = r0 + 1;

    const float4* xa = reinterpret_cast<const float4*>(x0) + r0 * NF4;
    const float4* xb = reinterpret_cast<const float4*>(x0) + r1 * NF4;

    float4 A[4], B[4];
#pragma unroll
    for (int j = 0; j < 4; ++j) A[j] = xa[j * 64 + lane];
#pragma unroll
    for (int j = 0; j < 4; ++j) B[j] = xb[j * 64 + lane];

    float da[NLAYERS] = {0.f, 0.f, 0.f, 0.f};
    float db[NLAYERS] = {0.f, 0.f, 0.f, 0.f};
#pragma unroll
    for (int j = 0; j < 4; ++j) {
        const int fi = j * 64 + lane;
#pragma unroll
        for (int l = 0; l < NLAYERS; ++l) {
            float4 wl = lW[l * NF4 + fi];
            da[l] += A[j].x * wl.x + A[j].y * wl.y + A[j].z * wl.z + A[j].w * wl.w;
            db[l] += B[j].x * wl.x + B[j].y * wl.y + B[j].z * wl.z + B[j].w * wl.w;
        }
    }

#pragma unroll
    for (int off = 32; off; off >>= 1) {
#pragma unroll
        for (int l = 0; l < NLAYERS; ++l) {
            da[l] += __shfl_xor(da[l], off, 64);
            db[l] += __shfl_xor(db[l], off, 64);
        }
    }

    float alA = 1.0f, alB = 1.0f;
    { float s = alA * da[0];            alA += s;
      s = fmaf(alA, da[1], cp1);        alA += s;
      s = fmaf(alA, da[2], cp2);        alA += s;
      s = fmaf(alA, da[3], cp3);        alA += s; }
    { float s = alB * db[0];            alB += s;
      s = fmaf(alB, db[1], cp1);        alB += s;
      s = fmaf(alB, db[2], cp2);        alB += s;
      s = fmaf(alB, db[3], cp3);        alB += s; }

    float4* oa = reinterpret_cast<float4*>(out) + r0 * NF4;
    float4* ob = reinterpret_cast<float4*>(out) + r1 * NF4;
#pragma unroll
    for (int j = 0; j < 4; ++j) {
        float4 o;
        o.x = fmaf(alA, A[j].x, bs[j].x);
        o.y = fmaf(alA, A[j].y, bs[j].y);
        o.z = fmaf(alA, A[j].z, bs[j].z);
        o.w = fmaf(alA, A[j].w, bs[j].w);
        oa[j * 64 + lane] = o;
    }
#pragma unroll
    for (int j = 0; j < 4; ++j) {
        float4 o;
        o.x = fmaf(alB, B[j].x, bs[j].x);
        o.y = fmaf(alB, B[j].y, bs[j].y);
        o.z = fmaf(alB, B[j].z, bs[j].z);
        o.w = fmaf(alB, B[j].w, bs[j].w);
        ob[j * 64 + lane] = o;
    }
}

extern "C" void kernel_launch(void* const* d_in, const int* in_sizes, int n_in,
                              void* d_out, int out_size, void* d_ws, size_t ws_size,
                              hipStream_t stream) {
    const float* x0 = (const float*)d_in[0];
    const float* W  = (const float*)d_in[1];
    const float* b  = (const float*)d_in[2];
    float* out      = (float*)d_out;

    crossnet_kernel<<<NBLOCKS, THREADS, 0, stream>>>(x0, W, b, out);
}

// Round 5
// 25.749 us; speedup vs baseline: 1.2710x; 1.0087x over previous
//
#include <hip/hip_runtime.h>

#define BATCH   16384
#define DIM     1024
#define NLAYERS 4
#define NF4     (DIM / 4)     // 256 float4 per row
#define THREADS 256           // 4 waves per block
#define NBLOCKS 2048          // 8192 waves x 2 concurrent rows = 16384 rows

typedef float floatx4 __attribute__((ext_vector_type(4)));   // native vec for nt-store

// x_L = alpha * x0 + bsum;  alpha = 1 + sum_l s_l,
// s_l = alpha_l * (x0 . W[l]) + c_l,  c_l = (sum_{k<l} b[k]) . W[l].
// Two rows per wave, barrier-free row phase. Output uses NON-TEMPORAL
// stores: out streams past the LLC so x0 stays L3-resident across graph
// replays -> read latency drops to L3-hit -> MLP-limited read BW rises.
__global__ __launch_bounds__(THREADS) void crossnet_kernel(
    const float* __restrict__ x0,
    const float* __restrict__ W,
    const float* __restrict__ b,
    float* __restrict__ out)
{
    __shared__ float4 lW[NLAYERS * NF4];   // 16 KB staged W
    __shared__ float4 lBsum[NF4];          //  4 KB
    __shared__ float  redc[3][4];

    const int tid  = threadIdx.x;
    const int lane = tid & 63;
    const int wv   = tid >> 6;

    const float4* Wv = reinterpret_cast<const float4*>(W);
    const float4* bv = reinterpret_cast<const float4*>(b);

    // ---- per-block prologue: stage W, build bsum and c_l constants ----
#pragma unroll
    for (int i = 0; i < NLAYERS * NF4 / THREADS; ++i)
        lW[tid + i * THREADS] = Wv[tid + i * THREADS];

    float4 b0 = bv[0 * NF4 + tid];
    float4 b1 = bv[1 * NF4 + tid];
    float4 b2 = bv[2 * NF4 + tid];
    float4 b3 = bv[3 * NF4 + tid];
    float4 w1 = Wv[1 * NF4 + tid];
    float4 w2 = Wv[2 * NF4 + tid];
    float4 w3 = Wv[3 * NF4 + tid];

    float4 pre = b0;
    float c1 = pre.x * w1.x + pre.y * w1.y + pre.z * w1.z + pre.w * w1.w;
    pre.x += b1.x; pre.y += b1.y; pre.z += b1.z; pre.w += b1.w;
    float c2 = pre.x * w2.x + pre.y * w2.y + pre.z * w2.z + pre.w * w2.w;
    pre.x += b2.x; pre.y += b2.y; pre.z += b2.z; pre.w += b2.w;
    float c3 = pre.x * w3.x + pre.y * w3.y + pre.z * w3.z + pre.w * w3.w;
    pre.x += b3.x; pre.y += b3.y; pre.z += b3.z; pre.w += b3.w;
    lBsum[tid] = pre;

#pragma unroll
    for (int off = 32; off; off >>= 1) {
        c1 += __shfl_xor(c1, off, 64);
        c2 += __shfl_xor(c2, off, 64);
        c3 += __shfl_xor(c3, off, 64);
    }
    if (lane == 0) { redc[0][wv] = c1; redc[1][wv] = c2; redc[2][wv] = c3; }
    __syncthreads();
    const float cp1 = redc[0][0] + redc[0][1] + redc[0][2] + redc[0][3];
    const float cp2 = redc[1][0] + redc[1][1] + redc[1][2] + redc[1][3];
    const float cp3 = redc[2][0] + redc[2][1] + redc[2][2] + redc[2][3];

    float4 bs[4];
#pragma unroll
    for (int j = 0; j < 4; ++j) bs[j] = lBsum[j * 64 + lane];

    // ---- two rows per wave, processed concurrently, no loop ----
    const int gw = blockIdx.x * (THREADS / 64) + wv;   // 0..8191
    const size_t r0 = (size_t)(2 * gw);
    const size_t r1 = r0 + 1;

    const float4* xa = reinterpret_cast<const float4*>(x0) + r0 * NF4;
    const float4* xb = reinterpret_cast<const float4*>(x0) + r1 * NF4;

    float4 A[4], B[4];
#pragma unroll
    for (int j = 0; j < 4; ++j) A[j] = xa[j * 64 + lane];
#pragma unroll
    for (int j = 0; j < 4; ++j) B[j] = xb[j * 64 + lane];

    float da[NLAYERS] = {0.f, 0.f, 0.f, 0.f};
    float db[NLAYERS] = {0.f, 0.f, 0.f, 0.f};
#pragma unroll
    for (int j = 0; j < 4; ++j) {
        const int fi = j * 64 + lane;
#pragma unroll
        for (int l = 0; l < NLAYERS; ++l) {
            float4 wl = lW[l * NF4 + fi];
            da[l] += A[j].x * wl.x + A[j].y * wl.y + A[j].z * wl.z + A[j].w * wl.w;
            db[l] += B[j].x * wl.x + B[j].y * wl.y + B[j].z * wl.z + B[j].w * wl.w;
        }
    }

#pragma unroll
    for (int off = 32; off; off >>= 1) {
#pragma unroll
        for (int l = 0; l < NLAYERS; ++l) {
            da[l] += __shfl_xor(da[l], off, 64);
            db[l] += __shfl_xor(db[l], off, 64);
        }
    }

    float alA = 1.0f, alB = 1.0f;
    { float s = alA * da[0];            alA += s;
      s = fmaf(alA, da[1], cp1);        alA += s;
      s = fmaf(alA, da[2], cp2);        alA += s;
      s = fmaf(alA, da[3], cp3);        alA += s; }
    { float s = alB * db[0];            alB += s;
      s = fmaf(alB, db[1], cp1);        alB += s;
      s = fmaf(alB, db[2], cp2);        alB += s;
      s = fmaf(alB, db[3], cp3);        alB += s; }

    floatx4* oa = reinterpret_cast<floatx4*>(out) + r0 * NF4;
    floatx4* ob = reinterpret_cast<floatx4*>(out) + r1 * NF4;
#pragma unroll
    for (int j = 0; j < 4; ++j) {
        floatx4 o;
        o.x = fmaf(alA, A[j].x, bs[j].x);
        o.y = fmaf(alA, A[j].y, bs[j].y);
        o.z = fmaf(alA, A[j].z, bs[j].z);
        o.w = fmaf(alA, A[j].w, bs[j].w);
        __builtin_nontemporal_store(o, &oa[j * 64 + lane]);
    }
#pragma unroll
    for (int j = 0; j < 4; ++j) {
        floatx4 o;
        o.x = fmaf(alB, B[j].x, bs[j].x);
        o.y = fmaf(alB, B[j].y, bs[j].y);
        o.z = fmaf(alB, B[j].z, bs[j].z);
        o.w = fmaf(alB, B[j].w, bs[j].w);
        __builtin_nontemporal_store(o, &ob[j * 64 + lane]);
    }
}

extern "C" void kernel_launch(void* const* d_in, const int* in_sizes, int n_in,
                              void* d_out, int out_size, void* d_ws, size_t ws_size,
                              hipStream_t stream) {
    const float* x0 = (const float*)d_in[0];
    const float* W  = (const float*)d_in[1];
    const float* b  = (const float*)d_in[2];
    float* out      = (float*)d_out;

    crossnet_kernel<<<NBLOCKS, THREADS, 0, stream>>>(x0, W, b, out);
}